// Round 7
// baseline (169.396 us; speedup 1.0000x reference)
//
#include <hip/hip_runtime.h>

// LocalAttention, MFMA bf16, round 14 = fully independent 1-wave blocks.
// B=4, L=2048, H=16, E=D=64, window=64. fp32 in/out; bf16 MFMA; fp32 accumulate.
//
// r7-r13 conclusion: four structurally different attempts to batch register-
// destined loads (sched_barrier, branchless, asm anchor x2, entry hoist) all
// failed (VGPR 52..104, dur 40-53us, BW 2.2-2.9 TB/s). The limiter is PHASE
// CORRELATION: a block-wide barrier makes all 4 waves load together then
// compute together with zero loads outstanding; 3 resident blocks -> ~50%
// memory duty = measured BW. Fix = remove the correlator entirely:
//
//   ONE WAVE PER BLOCK. 64-thread workgroups, each owning 16 queries x 80
//   keys with a PRIVATE Vt slice. No cross-wave barrier exists; a CU holds
//   12 independent instruction streams at uncorrelated phases, so the memory
//   pipe stays fed even with the compiler's chunked load rhythm:
//   P(no stream loading) ~ (1-d)^12 ~ 0.
//
//   - Swapped QK (r11-r13, verified): acc = mfma(K_frag, Q_frag) = S^T;
//     softmaxed P packs directly into PV A-frags in-register; softmax
//     reduce = shfl_xor 16,32. Pure-register QK (K frags from global;
//     halo re-reads served by L1/L2).
//   - V staged per wave -> transposed bf16 Vt[64][104] = 13312 B
//     -> 12 blocks/CU (12 x 13312 = 159.7 KB <= 160 KB, LDS-limited).
//   - Index-based masking neutralizes clamped K rows; Vt cols 80..95
//     zeroed (PV tail reads them; avoids NaN from uninit LDS).
//   - launch_bounds(64,3): VGPR cap 168, enough for natural pipelining.
// Grid (L/16, H, B) = (128,16,4) = 8192 one-wave blocks.

#define B_ 4
#define L_ 2048
#define H_ 16
#define E_ 64
#define D_ 64
#define VSTR 104   // bf16 per Vt row: 96 key cols (80 data + 16 zero) + 8 pad

typedef __attribute__((ext_vector_type(8))) short short8;
typedef __attribute__((ext_vector_type(4))) float f32x4;

__device__ __forceinline__ unsigned int f2bf(float x) {
  unsigned int b = __float_as_uint(x);
  b += 0x7fffu + ((b >> 16) & 1u);   // RNE to bf16
  return b >> 16;
}
__device__ __forceinline__ unsigned int pack2(float a, float b) {
  return f2bf(a) | (f2bf(b) << 16);
}
__device__ __forceinline__ short8 pack8(const f32x4& a, const f32x4& b) {
  union { short8 s; uint4 u; } r;
  r.u = make_uint4(pack2(a[0], a[1]), pack2(a[2], a[3]),
                   pack2(b[0], b[1]), pack2(b[2], b[3]));
  return r.s;
}
__device__ __forceinline__ int clampL(int k) {
  return k < 0 ? 0 : (k > (L_ - 1) ? (L_ - 1) : k);
}

__global__ __launch_bounds__(64, 3)
void local_attn_mfma(const float* __restrict__ qg,
                     const float* __restrict__ kg,
                     const float* __restrict__ vg,
                     float* __restrict__ og) {
  __shared__ __align__(16) unsigned short Vt[64 * VSTR];  // 13312 B, [dim][key_rel]

  const int lane = threadIdx.x;          // one wave
  const int q0 = blockIdx.x * 16;
  const int h = blockIdx.y;
  const int b = blockIdx.z;
  const int kstart = q0 - 32;            // keys [kstart, kstart+80)
  const int col16 = lane & 15;
  const int quad = lane >> 4;

  // ---- V staging: 5 chunks of 16 keys. lane = (key-pair p2, dim-octet o8).
  //      Pack fp32 -> bf16 pairs (2 adjacent keys, same dim) -> Vt[dim][key]. ----
  const int p2 = (lane >> 3) * 2;        // key pair base within chunk (0,2..14)
  const int o8 = (lane & 7) * 8;         // dim octet base (0,8..56)
  #pragma unroll
  for (int c = 0; c < 5; ++c) {
    const int k0 = clampL(kstart + c * 16 + p2);
    const int k1 = clampL(kstart + c * 16 + p2 + 1);
    const float* pv0 = vg + ((size_t)(b * L_ + k0) * H_ + h) * D_ + o8;
    const float* pv1 = vg + ((size_t)(b * L_ + k1) * H_ + h) * D_ + o8;
    const f32x4 a0 = *(const f32x4*)pv0;
    const f32x4 a1 = *(const f32x4*)(pv0 + 4);
    const f32x4 b0 = *(const f32x4*)pv1;
    const f32x4 b1 = *(const f32x4*)(pv1 + 4);
    #pragma unroll
    for (int j = 0; j < 4; ++j) {
      *(unsigned int*)&Vt[(o8 + j) * VSTR + c * 16 + p2] = pack2(a0[j], b0[j]);
      *(unsigned int*)&Vt[(o8 + 4 + j) * VSTR + c * 16 + p2] = pack2(a1[j], b1[j]);
    }
  }
  // zero-pad key cols 80..95 (PV tail reads them; P there is 0, but 0*NaN=NaN)
  #pragma unroll
  for (int i = 0; i < 4; ++i)
    *(uint2*)&Vt[lane * VSTR + 80 + i * 4] = make_uint2(0u, 0u);

  // ---- Q fragment (B-operand of swapped QK): Q[q0+col16][dims quad*8..] ----
  short8 qa0, qa1;
  {
    const float* pq = qg + ((size_t)(b * L_ + q0 + col16) * H_ + h) * E_ + quad * 8;
    qa0 = pack8(*(const f32x4*)pq, *(const f32x4*)(pq + 4));
    qa1 = pack8(*(const f32x4*)(pq + 32), *(const f32x4*)(pq + 36));
  }

  // ---- K fragments: 5 key-tiles direct from global (L1/L2-hot halo) ----
  short8 kb0[5], kb1[5];
  #pragma unroll
  for (int tt = 0; tt < 5; ++tt) {
    const int key = clampL(kstart + tt * 16 + col16);
    const float* pk = kg + ((size_t)(b * L_ + key) * H_ + h) * E_ + quad * 8;
    kb0[tt] = pack8(*(const f32x4*)pk, *(const f32x4*)(pk + 4));
    kb1[tt] = pack8(*(const f32x4*)(pk + 32), *(const f32x4*)(pk + 36));
  }

  // ---- QK swapped, pure-register MFMAs: acc = S^T.
  //      Lane holds S[key = tt*16 + quad*4 + r][query = col16]. ----
  f32x4 acc[5];
  #pragma unroll
  for (int tt = 0; tt < 5; ++tt) {
    f32x4 c = {0.f, 0.f, 0.f, 0.f};
    c = __builtin_amdgcn_mfma_f32_16x16x32_bf16(kb0[tt], qa0, c, 0, 0, 0);
    c = __builtin_amdgcn_mfma_f32_16x16x32_bf16(kb1[tt], qa1, c, 0, 0, 0);
    acc[tt] = c;
  }

  // ---- Mask + softmax. Query = col16; keys over (tt,quad,r).
  //      Cross-lane reduce = quads only: shfl_xor 16, 32. ----
  float mx = -1e30f;
  #pragma unroll
  for (int tt = 0; tt < 5; ++tt)
    #pragma unroll
    for (int r = 0; r < 4; ++r) {
      const int k_loc = tt * 16 + quad * 4 + r;          // key rel to kstart
      const int gkey = kstart + k_loc;                   // global key
      const bool ok = ((unsigned)(k_loc - col16) < 64u) &&
                      ((unsigned)gkey < (unsigned)L_);
      const float v = ok ? acc[tt][r] * 0.125f : -1e30f; // scale = 1/sqrt(64)
      acc[tt][r] = v;
      mx = fmaxf(mx, v);
    }
  mx = fmaxf(mx, __shfl_xor(mx, 16));
  mx = fmaxf(mx, __shfl_xor(mx, 32));
  float s = 0.f;
  #pragma unroll
  for (int tt = 0; tt < 5; ++tt)
    #pragma unroll
    for (int r = 0; r < 4; ++r) {
      const float e = __expf(acc[tt][r] - mx);
      acc[tt][r] = e;
      s += e;
    }
  s += __shfl_xor(s, 16);
  s += __shfl_xor(s, 32);
  const float inv = 1.0f / s;            // >= 32 valid keys -> s >= 1

  // ---- P -> PV A-frags IN REGISTER (lane-local by construction).
  //      elem j of pa[ks] = P[col16][32ks+16(j>>2)+4quad+(j&3)]
  //      = acc[2ks + (j>>2)][j&3]. Tail frag: elems 4..7 = 0. ----
  short8 pa[3];
  {
    union { short8 s8; uint4 u4; } w;
    w.u4 = make_uint4(pack2(acc[0][0] * inv, acc[0][1] * inv),
                      pack2(acc[0][2] * inv, acc[0][3] * inv),
                      pack2(acc[1][0] * inv, acc[1][1] * inv),
                      pack2(acc[1][2] * inv, acc[1][3] * inv));
    pa[0] = w.s8;
    w.u4 = make_uint4(pack2(acc[2][0] * inv, acc[2][1] * inv),
                      pack2(acc[2][2] * inv, acc[2][3] * inv),
                      pack2(acc[3][0] * inv, acc[3][1] * inv),
                      pack2(acc[3][2] * inv, acc[3][3] * inv));
    pa[1] = w.s8;
    w.u4 = make_uint4(pack2(acc[4][0] * inv, acc[4][1] * inv),
                      pack2(acc[4][2] * inv, acc[4][3] * inv), 0u, 0u);
    pa[2] = w.s8;
  }

  __syncthreads();   // 1-wave block: cheap; orders Vt writes before PV reads

  // ---- PV: per dim-tile nt, 3 K=32 steps. B elem j = V[key(quad*8+j)][dim]:
  //      two uint2 (4 consecutive keys each) at cols ks*32+quad*4 and +16. ----
  f32x4 oacc[4];
  #pragma unroll
  for (int nt = 0; nt < 4; ++nt) oacc[nt] = (f32x4){0.f, 0.f, 0.f, 0.f};
  #pragma unroll
  for (int nt = 0; nt < 4; ++nt) {
    const int rowb = (nt * 16 + col16) * VSTR;
    #pragma unroll
    for (int ks = 0; ks < 3; ++ks) {
      union { short8 s8; uint2 u2[2]; } vb;
      vb.u2[0] = *(const uint2*)&Vt[rowb + ks * 32 + quad * 4];
      vb.u2[1] = *(const uint2*)&Vt[rowb + ks * 32 + 16 + quad * 4];
      oacc[nt] = __builtin_amdgcn_mfma_f32_16x16x32_bf16(pa[ks], vb.s8, oacc[nt], 0, 0, 0);
    }
  }

  // ---- Store O (fp32). C: row = quad*4+r (query), col = col16 (dim) ----
  #pragma unroll
  for (int r = 0; r < 4; ++r) {
    const int q = q0 + quad * 4 + r;
    float* orow = og + ((size_t)(b * L_ + q) * H_ + h) * D_;
    #pragma unroll
    for (int nt = 0; nt < 4; ++nt)
      orow[nt * 16 + col16] = oacc[nt][r];
  }
}

extern "C" void kernel_launch(void* const* d_in, const int* in_sizes, int n_in,
                              void* d_out, int out_size, void* d_ws, size_t ws_size,
                              hipStream_t stream) {
  const float* q = (const float*)d_in[0];
  const float* k = (const float*)d_in[1];
  const float* v = (const float*)d_in[2];
  float* o = (float*)d_out;
  dim3 grid(L_ / 16, H_, B_);
  local_attn_mfma<<<grid, dim3(64), 0, stream>>>(q, k, v, o);
}

// Round 8
// 138.415 us; speedup vs baseline: 1.2238x; 1.2238x over previous
//
#include <hip/hip_runtime.h>

// LocalAttention, MFMA bf16, round 15 = ALL staging via global_load_lds (fire-and-forget).
// B=4, L=2048, H=16, E=D=64, window=64. fp32 in/out; bf16 MFMA; fp32 accumulate.
//
// r14 post-mortem: 12 independent 1-wave streams/CU reached only 3.0 TB/s while
// FETCH doubled (16-q tiles re-read halo 5x) -> dur 72us. Series invariant:
// duration == traffic / ~2.9 TB/s in every structure tried. Before declaring a
// pattern ceiling, run the one clean experiment: ZERO register-destined staging.
//
//   - 64-query / 4-wave blocks (best traffic shape: FETCH ~81 MB).
//   - K, V, AND Q staged fp32 by global_load_lds: ~20 DMA issues per wave,
//     no dest regs, nothing can serialize them, ONE barrier wait total.
//     This is structurally how fillBuffer drives 6.6 TB/s.
//   - K/Q source-chunk XOR swizzle (r12-verified): slot(row,c) holds global
//     chunk c^(row&15); readers use slot g^col16 (row&15==col16 always).
//   - V staged LINEAR [key][dim]; PV gathers 8 scalars/MFMA (4-way bank
//     conflict accepted; swizzling V costs more VALU than it saves).
//     Overhang band keys 80..95/wave: P==0 exactly; read slot&127 (16 ands)
//     instead of padding rows, so LDS = 32+32+16 = 80 KB -> 2 blocks/CU.
//   - Swapped QK + in-register P (r11-r14 verified), index-based masking.
//
// TELL: hbm_gbps > 3.8 => compiler serialization was the limiter all along.
//       hbm_gbps <= 3.1 => ~3 TB/s is this pattern's ceiling; declare roofline.

#define B_ 4
#define L_ 2048
#define H_ 16
#define E_ 64
#define D_ 64

typedef __attribute__((ext_vector_type(8))) short short8;
typedef __attribute__((ext_vector_type(4))) float f32x4;

__device__ __forceinline__ unsigned int f2bf(float x) {
  unsigned int b = __float_as_uint(x);
  b += 0x7fffu + ((b >> 16) & 1u);   // RNE to bf16
  return b >> 16;
}
__device__ __forceinline__ unsigned int pack2(float a, float b) {
  return f2bf(a) | (f2bf(b) << 16);
}
__device__ __forceinline__ short8 pack8(const f32x4& a, const f32x4& b) {
  union { short8 s; uint4 u; } r;
  r.u = make_uint4(pack2(a[0], a[1]), pack2(a[2], a[3]),
                   pack2(b[0], b[1]), pack2(b[2], b[3]));
  return r.s;
}
__device__ __forceinline__ int clampL(int k) {
  return k < 0 ? 0 : (k > (L_ - 1) ? (L_ - 1) : k);
}

__global__ __launch_bounds__(256, 2)
void local_attn_mfma(const float* __restrict__ qg,
                     const float* __restrict__ kg,
                     const float* __restrict__ vg,
                     float* __restrict__ og) {
  __shared__ __align__(16) float Ks32[128 * 64];  // 32 KB, chunk-swizzled
  __shared__ __align__(16) float Vs32[128 * 64];  // 32 KB, linear [key][dim]
  __shared__ __align__(16) float Qs32[64 * 64];   // 16 KB, chunk-swizzled

  const int t = threadIdx.x;
  const int q0 = blockIdx.x * 64;
  const int h = blockIdx.y;
  const int b = blockIdx.z;
  const int kstart = q0 - 32;
  const int wave = t >> 6;
  const int lane = t & 63;
  const int col16 = lane & 15;
  const int quad = lane >> 4;

  // ---- K staging: 8x global_load_lds, source chunk-swizzled ----
  #pragma unroll
  for (int it = 0; it < 8; ++it) {
    const int cid = t + it * 256;
    const int row = cid >> 4, ch = cid & 15;
    const int chs = ch ^ (row & 15);
    const int key = clampL(kstart + row);
    const float* src = kg + ((size_t)(b * L_ + key) * H_ + h) * E_ + chs * 4;
    float* dst = &Ks32[(it * 256 + wave * 64) * 4];
    __builtin_amdgcn_global_load_lds(
        (__attribute__((address_space(1))) void*)src,
        (__attribute__((address_space(3))) void*)dst, 16, 0, 0);
  }
  // ---- V staging: 8x global_load_lds, LINEAR ----
  #pragma unroll
  for (int it = 0; it < 8; ++it) {
    const int cid = t + it * 256;
    const int row = cid >> 4, ch = cid & 15;
    const int key = clampL(kstart + row);
    const float* src = vg + ((size_t)(b * L_ + key) * H_ + h) * D_ + ch * 4;
    float* dst = &Vs32[(it * 256 + wave * 64) * 4];
    __builtin_amdgcn_global_load_lds(
        (__attribute__((address_space(1))) void*)src,
        (__attribute__((address_space(3))) void*)dst, 16, 0, 0);
  }
  // ---- Q staging: 4x global_load_lds, source chunk-swizzled ----
  #pragma unroll
  for (int it = 0; it < 4; ++it) {
    const int cid = t + it * 256;
    const int row = cid >> 4, ch = cid & 15;   // row = query 0..63, in range
    const int chs = ch ^ (row & 15);
    const float* src = qg + ((size_t)(b * L_ + q0 + row) * H_ + h) * E_ + chs * 4;
    float* dst = &Qs32[(it * 256 + wave * 64) * 4];
    __builtin_amdgcn_global_load_lds(
        (__attribute__((address_space(1))) void*)src,
        (__attribute__((address_space(3))) void*)dst, 16, 0, 0);
  }

  __syncthreads();   // the ONLY wait: drains all ~80 KB of DMA

  // ---- Fragment reads. Swizzled chunk slots: g ^ col16 (row&15 == col16) ----
  const int s0 = (2 * quad) ^ col16;
  const int s1 = (2 * quad + 1) ^ col16;
  const int s2 = (2 * quad + 8) ^ col16;
  const int s3 = (2 * quad + 9) ^ col16;

  short8 qa0, qa1;
  {
    const float* Qr = &Qs32[(wave * 16 + col16) * 64];
    qa0 = pack8(*(const f32x4*)(Qr + s0 * 4), *(const f32x4*)(Qr + s1 * 4));
    qa1 = pack8(*(const f32x4*)(Qr + s2 * 4), *(const f32x4*)(Qr + s3 * 4));
  }

  // ---- QK swapped: acc = S^T. Lane: S[key=wave*16+tt*16+quad*4+r][q=col16] ----
  f32x4 acc[5];
  #pragma unroll
  for (int tt = 0; tt < 5; ++tt) {
    const int krow = wave * 16 + tt * 16 + col16;
    const float* Kr = &Ks32[krow * 64];
    const short8 kb0 = pack8(*(const f32x4*)(Kr + s0 * 4), *(const f32x4*)(Kr + s1 * 4));
    const short8 kb1 = pack8(*(const f32x4*)(Kr + s2 * 4), *(const f32x4*)(Kr + s3 * 4));
    f32x4 c = {0.f, 0.f, 0.f, 0.f};
    c = __builtin_amdgcn_mfma_f32_16x16x32_bf16(kb0, qa0, c, 0, 0, 0);
    c = __builtin_amdgcn_mfma_f32_16x16x32_bf16(kb1, qa1, c, 0, 0, 0);
    acc[tt] = c;
  }

  // ---- Mask + softmax (query=col16; keys over tt,quad,r; reduce 16,32) ----
  float mx = -1e30f;
  #pragma unroll
  for (int tt = 0; tt < 5; ++tt)
    #pragma unroll
    for (int r = 0; r < 4; ++r) {
      const int k_loc = tt * 16 + quad * 4 + r;          // key rel to wave band
      const int gkey = kstart + wave * 16 + k_loc;       // global key
      const bool ok = ((unsigned)(k_loc - col16) < 64u) &&
                      ((unsigned)gkey < (unsigned)L_);
      const float v = ok ? acc[tt][r] * 0.125f : -1e30f; // scale = 1/sqrt(64)
      acc[tt][r] = v;
      mx = fmaxf(mx, v);
    }
  mx = fmaxf(mx, __shfl_xor(mx, 16));
  mx = fmaxf(mx, __shfl_xor(mx, 32));
  float s = 0.f;
  #pragma unroll
  for (int tt = 0; tt < 5; ++tt)
    #pragma unroll
    for (int r = 0; r < 4; ++r) {
      const float e = __expf(acc[tt][r] - mx);
      acc[tt][r] = e;
      s += e;
    }
  s += __shfl_xor(s, 16);
  s += __shfl_xor(s, 32);
  const float inv = 1.0f / s;            // >= 32 valid keys -> s >= 1

  // ---- P -> PV A-frags IN REGISTER: pa[ks] elem j = acc[2ks+(j>>2)][j&3] ----
  short8 pa[3];
  {
    union { short8 s8; uint4 u4; } w;
    w.u4 = make_uint4(pack2(acc[0][0] * inv, acc[0][1] * inv),
                      pack2(acc[0][2] * inv, acc[0][3] * inv),
                      pack2(acc[1][0] * inv, acc[1][1] * inv),
                      pack2(acc[1][2] * inv, acc[1][3] * inv));
    pa[0] = w.s8;
    w.u4 = make_uint4(pack2(acc[2][0] * inv, acc[2][1] * inv),
                      pack2(acc[2][2] * inv, acc[2][3] * inv),
                      pack2(acc[3][0] * inv, acc[3][1] * inv),
                      pack2(acc[3][2] * inv, acc[3][3] * inv));
    pa[1] = w.s8;
    w.u4 = make_uint4(pack2(acc[4][0] * inv, acc[4][1] * inv),
                      pack2(acc[4][2] * inv, acc[4][3] * inv), 0u, 0u);
    pa[2] = w.s8;
  }

  // ---- PV: B elem j = V[slot][dim], slot = wave*16+32ks+16(j>>2)+4quad+(j&3),
  //      dim = nt*16+col16. Overhang slots (ks==2, j>=4) -> &127 (P==0 there). ----
  f32x4 oacc[4];
  #pragma unroll
  for (int nt = 0; nt < 4; ++nt) oacc[nt] = (f32x4){0.f, 0.f, 0.f, 0.f};
  #pragma unroll
  for (int nt = 0; nt < 4; ++nt) {
    const int dim = nt * 16 + col16;
    #pragma unroll
    for (int ks = 0; ks < 3; ++ks) {
      f32x4 va, vb4;
      #pragma unroll
      for (int j = 0; j < 8; ++j) {
        int slot = wave * 16 + ks * 32 + ((j >> 2) << 4) + quad * 4 + (j & 3);
        if (ks == 2 && j >= 4) slot &= 127;   // compile-time-resolved guard
        const float vv = Vs32[slot * 64 + dim];
        if (j < 4) va[j] = vv; else vb4[j - 4] = vv;
      }
      oacc[nt] = __builtin_amdgcn_mfma_f32_16x16x32_bf16(pa[ks], pack8(va, vb4), oacc[nt], 0, 0, 0);
    }
  }

  // ---- Store O (fp32). C: row = quad*4+r (query), col = col16 (dim) ----
  #pragma unroll
  for (int r = 0; r < 4; ++r) {
    const int q = q0 + wave * 16 + quad * 4 + r;
    float* orow = og + ((size_t)(b * L_ + q) * H_ + h) * D_;
    #pragma unroll
    for (int nt = 0; nt < 4; ++nt)
      orow[nt * 16 + col16] = oacc[nt][r];
  }
}

extern "C" void kernel_launch(void* const* d_in, const int* in_sizes, int n_in,
                              void* d_out, int out_size, void* d_ws, size_t ws_size,
                              hipStream_t stream) {
  const float* q = (const float*)d_in[0];
  const float* k = (const float*)d_in[1];
  const float* v = (const float*)d_in[2];
  float* o = (float*)d_out;
  dim3 grid(L_ / 64, H_, B_);
  local_attn_mfma<<<grid, dim3(256), 0, stream>>>(q, k, v, o);
}